// Round 4
// baseline (313.724 us; speedup 1.0000x reference)
//
#include <hip/hip_runtime.h>
#include <hip/hip_bf16.h>

#define Qn 2048
#define Kn 2048
#define Cin 128
#define Hn 8
#define CHn 32
#define HDn 256
#define NSPLIT 8
#define DSTR 260            // padded LDS row stride in floats (1040 B): bank-rotates q
#define DBUF (16 * DSTR)    // floats per dist tile buffer

typedef __attribute__((ext_vector_type(8))) short short8;
typedef __attribute__((ext_vector_type(4))) float f32x4;

static __device__ __forceinline__ unsigned short f2bf(float f) {
    unsigned int u = __float_as_uint(f);
    u += 0x7fffu + ((u >> 16) & 1u);
    return (unsigned short)(u >> 16);
}

// async global->LDS (gfx950). Global src PER-LANE; LDS dst = uniform base + lane*size.
static __device__ __forceinline__ void ld16(const void* g, void* l) {
    __builtin_amdgcn_global_load_lds(
        (const __attribute__((address_space(1))) void*)g,
        (__attribute__((address_space(3))) void*)l, 16, 0, 0);
}
static __device__ __forceinline__ void ld4(const void* g, void* l) {
    __builtin_amdgcn_global_load_lds(
        (const __attribute__((address_space(1))) void*)g,
        (__attribute__((address_space(3))) void*)l, 4, 0, 0);
}

// ---------------------------------------------------------------------------
// K1: projections. q=(qx@Wq)/sqrt(CH)->bf16 [Q][HD]; k=kvx@Wk->bf16 [K][HD];
//     v=kvx@Wv->bf16 TRANSPOSED [HD][K]; g=sigmoid(qx@Wg+bg)->f32 [Q][HD].
// ---------------------------------------------------------------------------
__global__ __launch_bounds__(256) void proj_kernel(
    const float* __restrict__ qx, const float* __restrict__ kvx,
    const float* __restrict__ Wq, const float* __restrict__ Wk,
    const float* __restrict__ Wv, const float* __restrict__ Wg,
    const float* __restrict__ bg,
    unsigned short* __restrict__ qb, unsigned short* __restrict__ kb,
    unsigned short* __restrict__ vtb, float* __restrict__ gb)
{
    const int mat = blockIdx.y;
    const int r0 = blockIdx.x * 8;
    const int j = threadIdx.x;
    const float* A = (mat == 0 || mat == 3) ? qx : kvx;
    const float* W = (mat == 0) ? Wq : (mat == 1) ? Wk : (mat == 2) ? Wv : Wg;
    const float* Ar = A + r0 * Cin;
    float acc[8] = {0.f, 0.f, 0.f, 0.f, 0.f, 0.f, 0.f, 0.f};
    for (int c = 0; c < Cin; ++c) {
        const float w = W[c * HDn + j];
        #pragma unroll
        for (int i = 0; i < 8; ++i)
            acc[i] = fmaf(Ar[i * Cin + c], w, acc[i]);
    }
    if (mat == 0) {
        const float s = 0.17677669529663687f; // 1/sqrt(32)
        #pragma unroll
        for (int i = 0; i < 8; ++i)
            qb[(r0 + i) * HDn + j] = f2bf(acc[i] * s);
    } else if (mat == 1) {
        #pragma unroll
        for (int i = 0; i < 8; ++i)
            kb[(r0 + i) * HDn + j] = f2bf(acc[i]);
    } else if (mat == 2) {
        unsigned short tmp[8];
        #pragma unroll
        for (int i = 0; i < 8; ++i) tmp[i] = f2bf(acc[i]);
        *(short8*)(vtb + (size_t)j * Kn + r0) = *(short8*)tmp;
    } else {
        const float b = bg[j];
        #pragma unroll
        for (int i = 0; i < 8; ++i)
            gb[(r0 + i) * HDn + j] = 1.f / (1.f + __expf(-(acc[i] + b)));
    }
}

// ---------------------------------------------------------------------------
// K2: fused attention. Grid 1024 = 128 q-tiles x 8 K-splits, 512 thr = 8 waves
// (wave == head). KVBLK=32, 8 tiles/block.
//
// THIS ROUND:
// (a) dist staged TRANSPOSED: per q-row LDS layout [h][k] via size-4
//     global_load_lds with per-lane gathered global addresses (the global
//     side is per-lane; LDS side stays linear). Row stride DSTR=260 floats
//     rotates banks by 4 per q => exp-phase reads are 2-way (free) instead
//     of the 16-way conflict of the [k][h] layout (R3: 8.65M conflicts).
// (b) 3-deep dist pipeline with COUNTED drain: stage(kt+2) issued in iter kt;
//     top-of-tile wait is vmcnt(8) -- in-order retirement makes this exactly
//     "everything older than stage(kt+1) retired, stage(kt+1) in flight".
//     Steady-state wall per tile = max(C, L/2) instead of L.
// (c) bias staged once for the whole 256-k split (16 rows x 256, ld16,
//     DSTR-padded => 2-way reads).
// LDS: 3*16.25(dist) + 16.25(bias) + 10(ps) = 75 KB -> 2 blocks/CU.
// No-max softmax safe: |logit| < 8.
// ---------------------------------------------------------------------------
__global__ __launch_bounds__(512, 4) void attn_kernel(
    const unsigned short* __restrict__ qb, const unsigned short* __restrict__ kb,
    const unsigned short* __restrict__ vtb,
    const float* __restrict__ bias, const float* __restrict__ dist,
    float* __restrict__ opart, float* __restrict__ lpart)
{
    __shared__ float dl[3 * DBUF];            // 48.75 KB, [buf][q][h][k] (k inner, 32)
    __shared__ float bl[16 * DSTR];           // 16.25 KB, [q][k-split]
    __shared__ unsigned short ps[Hn][16][40]; // 10 KB, P round-trip

    const int bx = blockIdx.x;
    const int qt = bx >> 3;
    const int sp = bx & 7;
    const int q0 = qt * 16;
    const int k00 = sp * 256;
    const int t = threadIdx.x;
    const int h = t >> 6;   // wave id == head
    const int l = t & 63;
    const int g = l >> 4;
    const int n = l & 15;

    const short8 qf = *(const short8*)(qb + (q0 + n) * HDn + h * CHn + g * 8);

    f32x4 o0 = {0.f, 0.f, 0.f, 0.f};
    f32x4 o1 = {0.f, 0.f, 0.f, 0.f};
    float lacc[4] = {0.f, 0.f, 0.f, 0.f};
    unsigned short* psh = &ps[h][0][0];
    const f32x4 z = {0.f, 0.f, 0.f, 0.f};

    // dist transposed staging: wave h stages q-local rows h and h+8.
    // Instr i (i=0..3) of a row writes LDS floats [i*64 + lane] = h_d*32 + k_l
    // with h_d = 2i + (l>>5), k_l = l&31; global float = rowbase + k_l*8 + h_d.
    const int dloff = (l & 31) * 8 + (l >> 5);   // + 2*i per instruction
    const float* dgA = dist + (size_t)(q0 + h) * Kn * Hn;
    const float* dgB = dist + (size_t)(q0 + h + 8) * Kn * Hn;

    short8 kf[2][2], vf[2][2];

    #define STAGE(buf, kt_) do {                                              \
        const float* gA_ = dgA + (size_t)(k00 + (kt_) * 32) * Hn + dloff;     \
        const float* gB_ = dgB + (size_t)(k00 + (kt_) * 32) * Hn + dloff;     \
        float* lA_ = dl + (buf) * DBUF + h * DSTR;                            \
        float* lB_ = dl + (buf) * DBUF + (h + 8) * DSTR;                      \
        _Pragma("unroll") for (int i_ = 0; i_ < 4; ++i_) {                    \
            ld4(gA_ + 2 * i_, lA_ + i_ * 64);                                 \
            ld4(gB_ + 2 * i_, lB_ + i_ * 64);                                 \
        }                                                                     \
    } while (0)

    #define KVLOAD(set, kt_) do {                                             \
        const int k0v = k00 + (kt_) * 32;                                      \
        kf[set][0] = *(const short8*)(kb + (k0v + n) * HDn + h * CHn + g * 8);      \
        kf[set][1] = *(const short8*)(kb + (k0v + 16 + n) * HDn + h * CHn + g * 8); \
        vf[set][0] = *(const short8*)(vtb + (h * CHn + n) * Kn + k0v + g * 8);      \
        vf[set][1] = *(const short8*)(vtb + (h * CHn + 16 + n) * Kn + k0v + g * 8); \
    } while (0)

    // prologue: bias (rows 2h, 2h+1), stage(0), KV(0), stage(1)
    ld16(bias + (size_t)(q0 + 2 * h) * Kn + k00 + l * 4, bl + (2 * h) * DSTR);
    ld16(bias + (size_t)(q0 + 2 * h + 1) * Kn + k00 + l * 4, bl + (2 * h + 1) * DSTR);
    __builtin_amdgcn_sched_barrier(0);
    STAGE(0, 0);
    __builtin_amdgcn_sched_barrier(0);
    KVLOAD(0, 0);
    __builtin_amdgcn_sched_barrier(0);
    STAGE(1, 1);
    __builtin_amdgcn_sched_barrier(0);

    #pragma unroll
    for (int kt = 0; kt < 8; ++kt) {
        const int cb = kt % 3;
        const int cur = kt & 1;
        // counted drain: everything older than stage(kt+1) retired;
        // stage(kt+1)'s 8 ld4 stay in flight across the barrier.
        if (kt < 7) asm volatile("s_waitcnt vmcnt(8)\n\ts_barrier" ::: "memory");
        else        asm volatile("s_waitcnt vmcnt(4)\n\ts_barrier" ::: "memory");
        if (kt < 7) { KVLOAD(cur ^ 1, kt + 1); __builtin_amdgcn_sched_barrier(0); }
        if (kt < 6) { STAGE((kt + 2) % 3, kt + 2); __builtin_amdgcn_sched_barrier(0); }

        // QK^T (kf issued one tile ago; compiler-counted wait leaves stages in flight)
        f32x4 sf[2];
        sf[0] = __builtin_amdgcn_mfma_f32_16x16x32_bf16(qf, kf[cur][0], z, 0, 0, 0);
        sf[1] = __builtin_amdgcn_mfma_f32_16x16x32_bf16(qf, kf[cur][1], z, 0, 0, 0);

        // p = exp(s + dist + bias); row sums; P -> LDS bf16. All LDS reads 2-way.
        const float* dlc = dl + cb * DBUF;
        #pragma unroll
        for (int kk = 0; kk < 2; ++kk) {
            #pragma unroll
            for (int r = 0; r < 4; ++r) {
                const int q_l = g * 4 + r;
                const float p = __expf(sf[kk][r]
                                       + dlc[q_l * DSTR + h * 32 + kk * 16 + n]
                                       + bl[q_l * DSTR + kt * 32 + kk * 16 + n]);
                sf[kk][r] = p;
                lacc[r] += p;
                psh[q_l * 40 + kk * 16 + n] = f2bf(p);
            }
        }

        // PV (vf issued one tile ago)
        const short8 pf = *(const short8*)(psh + n * 40 + g * 8);
        o0 = __builtin_amdgcn_mfma_f32_16x16x32_bf16(pf, vf[cur][0], o0, 0, 0, 0);
        o1 = __builtin_amdgcn_mfma_f32_16x16x32_bf16(pf, vf[cur][1], o1, 0, 0, 0);
    }
    #undef STAGE
    #undef KVLOAD

    // write partial O and row-sums
    float* op = opart + (size_t)sp * (Qn * HDn);
    #pragma unroll
    for (int r = 0; r < 4; ++r) {
        const int qg = q0 + g * 4 + r;
        op[qg * HDn + h * CHn + n] = o0[r];
        op[qg * HDn + h * CHn + 16 + n] = o1[r];
        float v = lacc[r];
        v += __shfl_xor(v, 1);
        v += __shfl_xor(v, 2);
        v += __shfl_xor(v, 4);
        v += __shfl_xor(v, 8);
        lacc[r] = v;
    }
    if (n == 0) {
        float* lp = lpart + (size_t)sp * (Qn * Hn);
        #pragma unroll
        for (int r = 0; r < 4; ++r)
            lp[(q0 + g * 4 + r) * Hn + h] = lacc[r];
    }
}

// ---------------------------------------------------------------------------
// K3: merge splits + gating + output projection. One block per q-row.
// ---------------------------------------------------------------------------
__global__ __launch_bounds__(256) void mergeout_kernel(
    const float* __restrict__ opart, const float* __restrict__ lpart,
    const float* __restrict__ gb, const float* __restrict__ Wo,
    const float* __restrict__ bo, float* __restrict__ out)
{
    __shared__ float olds[HDn];
    __shared__ float red[4][128];
    const int q = blockIdx.x;
    const int t = threadIdx.x;
    const int h = t >> 5;
    float s = 0.f;
    #pragma unroll
    for (int sp = 0; sp < NSPLIT; ++sp)
        s += opart[(size_t)sp * (Qn * HDn) + q * HDn + t];
    float lt = 0.f;
    #pragma unroll
    for (int sp = 0; sp < NSPLIT; ++sp)
        lt += lpart[(size_t)sp * (Qn * Hn) + q * Hn + h];
    olds[t] = (s / lt) * gb[q * HDn + t];
    __syncthreads();
    const int p = t & 63;
    const int seg = t >> 6;
    float a0 = 0.f, a1 = 0.f;
    for (int c = seg * 64; c < seg * 64 + 64; ++c) {
        const float ov = olds[c];
        const float2 w = *(const float2*)(Wo + c * Cin + 2 * p);
        a0 = fmaf(ov, w.x, a0);
        a1 = fmaf(ov, w.y, a1);
    }
    red[seg][2 * p] = a0;
    red[seg][2 * p + 1] = a1;
    __syncthreads();
    if (t < 128)
        out[q * Cin + t] = red[0][t] + red[1][t] + red[2][t] + red[3][t] + bo[t];
}

extern "C" void kernel_launch(void* const* d_in, const int* in_sizes, int n_in,
                              void* d_out, int out_size, void* d_ws, size_t ws_size,
                              hipStream_t stream)
{
    const float* qx   = (const float*)d_in[0];
    const float* kvx  = (const float*)d_in[1];
    const float* bias = (const float*)d_in[2];
    const float* dist = (const float*)d_in[3];
    const float* Wq   = (const float*)d_in[4];
    const float* Wk   = (const float*)d_in[5];
    const float* Wv   = (const float*)d_in[6];
    const float* Wg   = (const float*)d_in[7];
    const float* bg   = (const float*)d_in[8];
    const float* Wo   = (const float*)d_in[9];
    const float* bo   = (const float*)d_in[10];
    float* out = (float*)d_out;

    char* w = (char*)d_ws;
    unsigned short* qb  = (unsigned short*)(w);                  // 1 MB
    unsigned short* kb  = (unsigned short*)(w + (1ull << 20));   // 1 MB
    unsigned short* vtb = (unsigned short*)(w + (2ull << 20));   // 1 MB
    float* gb    = (float*)(w + (3ull << 20));                   // 2 MB
    float* opart = (float*)(w + (5ull << 20));                   // 16 MB (8 splits)
    float* lpart = (float*)(w + (21ull << 20));                  // 512 KB

    proj_kernel<<<dim3(Qn / 8, 4), 256, 0, stream>>>(qx, kvx, Wq, Wk, Wv, Wg, bg, qb, kb, vtb, gb);
    attn_kernel<<<dim3(128 * NSPLIT), 512, 0, stream>>>(qb, kb, vtb, bias, dist, opart, lpart);
    mergeout_kernel<<<dim3(Qn), 256, 0, stream>>>(opart, lpart, gb, Wo, bo, out);
}

// Round 5
// 280.994 us; speedup vs baseline: 1.1165x; 1.1165x over previous
//
#include <hip/hip_runtime.h>
#include <hip/hip_bf16.h>

#define Qn 2048
#define Kn 2048
#define Cin 128
#define Hn 8
#define CHn 32
#define HDn 256
#define NSPLIT 8
#define BSTR 260            // bias LDS row stride in floats (16B-aligned, 2-way reads)

typedef __attribute__((ext_vector_type(8))) short short8;
typedef __attribute__((ext_vector_type(4))) float f32x4;

static __device__ __forceinline__ unsigned short f2bf(float f) {
    unsigned int u = __float_as_uint(f);
    u += 0x7fffu + ((u >> 16) & 1u);
    return (unsigned short)(u >> 16);
}

// async global->LDS (gfx950). Global src PER-LANE; LDS dst = uniform base + lane*size.
static __device__ __forceinline__ void ld16(const void* g, void* l) {
    __builtin_amdgcn_global_load_lds(
        (const __attribute__((address_space(1))) void*)g,
        (__attribute__((address_space(3))) void*)l, 16, 0, 0);
}

// ---------------------------------------------------------------------------
// K1: projections. q=(qx@Wq)/sqrt(CH)->bf16 [Q][HD]; k=kvx@Wk->bf16 [K][HD];
//     v=kvx@Wv->bf16 TRANSPOSED [HD][K]; g=sigmoid(qx@Wg+bg)->f32 [Q][HD].
// ---------------------------------------------------------------------------
__global__ __launch_bounds__(256) void proj_kernel(
    const float* __restrict__ qx, const float* __restrict__ kvx,
    const float* __restrict__ Wq, const float* __restrict__ Wk,
    const float* __restrict__ Wv, const float* __restrict__ Wg,
    const float* __restrict__ bg,
    unsigned short* __restrict__ qb, unsigned short* __restrict__ kb,
    unsigned short* __restrict__ vtb, float* __restrict__ gb)
{
    const int mat = blockIdx.y;
    const int r0 = blockIdx.x * 8;
    const int j = threadIdx.x;
    const float* A = (mat == 0 || mat == 3) ? qx : kvx;
    const float* W = (mat == 0) ? Wq : (mat == 1) ? Wk : (mat == 2) ? Wv : Wg;
    const float* Ar = A + r0 * Cin;
    float acc[8] = {0.f, 0.f, 0.f, 0.f, 0.f, 0.f, 0.f, 0.f};
    for (int c = 0; c < Cin; ++c) {
        const float w = W[c * HDn + j];
        #pragma unroll
        for (int i = 0; i < 8; ++i)
            acc[i] = fmaf(Ar[i * Cin + c], w, acc[i]);
    }
    if (mat == 0) {
        const float s = 0.17677669529663687f; // 1/sqrt(32)
        #pragma unroll
        for (int i = 0; i < 8; ++i)
            qb[(r0 + i) * HDn + j] = f2bf(acc[i] * s);
    } else if (mat == 1) {
        #pragma unroll
        for (int i = 0; i < 8; ++i)
            kb[(r0 + i) * HDn + j] = f2bf(acc[i]);
    } else if (mat == 2) {
        unsigned short tmp[8];
        #pragma unroll
        for (int i = 0; i < 8; ++i) tmp[i] = f2bf(acc[i]);
        *(short8*)(vtb + (size_t)j * Kn + r0) = *(short8*)tmp;
    } else {
        const float b = bg[j];
        #pragma unroll
        for (int i = 0; i < 8; ++i)
            gb[(r0 + i) * HDn + j] = 1.f / (1.f + __expf(-(acc[i] + b)));
    }
}

// ---------------------------------------------------------------------------
// K2: fused attention. Grid 1024 = 128 q-tiles x 8 K-splits, 512 thr = 8 waves
// (wave == head). KVBLK=32, 8 tiles/block.
//
// THIS ROUND: R3's coalesced ld16 staging (2 instr/wave/tile, line-perfect) +
// R4's counted-vmcnt deep pipeline (3 dist buffers, stage kt+2 issued in iter
// kt). Steady state keeps TWO full dist stages (64 KB/block) in the VMEM
// queue at all times -> wall/tile ~ max(C, L/2) instead of L.
// In-order vmcnt accounting at top of iter kt (oldest first):
//   STAGE(kt)(2 ld16), KVLOAD(kt)(4), STAGE(kt+1)(2)  -> wait vmcnt(6)
// retires exactly this tile's dist; stage(kt+1) + KV stay in flight across
// the barrier. kf/vf mid-tile waits are compiler-counted. Dist LDS reads are
// 16-way bank-conflicted ([k][h] layout) — measured cheap (~130 cy/wave/tile),
// vs R4's conflict-free-but-scattered staging which cost 35 us of VMEM
// request amplification. No-max softmax safe: |logit| < 8.
// LDS: 48K dist + 16.6K bias + 10K ps = 74.8 KB -> 2 blocks/CU.
// ---------------------------------------------------------------------------
__global__ __launch_bounds__(512, 4) void attn_kernel(
    const unsigned short* __restrict__ qb, const unsigned short* __restrict__ kb,
    const unsigned short* __restrict__ vtb,
    const float* __restrict__ bias, const float* __restrict__ dist,
    float* __restrict__ opart, float* __restrict__ lpart)
{
    __shared__ float dl[3][16][256];          // 48 KB  [buf][q][k*8+h]
    __shared__ float bl[16 * BSTR];           // 16.6 KB [q][k-split]
    __shared__ unsigned short ps[Hn][16][40]; // 10 KB, P round-trip

    const int bx = blockIdx.x;
    const int qt = bx >> 3;
    const int sp = bx & 7;
    const int q0 = qt * 16;
    const int k00 = sp * 256;
    const int t = threadIdx.x;
    const int h = t >> 6;   // wave id == head
    const int l = t & 63;
    const int g = l >> 4;
    const int n = l & 15;

    const short8 qf = *(const short8*)(qb + (q0 + n) * HDn + h * CHn + g * 8);

    f32x4 o0 = {0.f, 0.f, 0.f, 0.f};
    f32x4 o1 = {0.f, 0.f, 0.f, 0.f};
    float lacc[4] = {0.f, 0.f, 0.f, 0.f};
    unsigned short* psh = &ps[h][0][0];
    const f32x4 z = {0.f, 0.f, 0.f, 0.f};

    // coalesced staging sources: wave h stages q-local rows h and h+8; one
    // ld16 covers a full row-tile (32 k x 8 h = 1024 B contiguous).
    const float* dsrcA = dist + (size_t)(q0 + h) * Kn * Hn + l * 4;
    const float* dsrcB = dist + (size_t)(q0 + h + 8) * Kn * Hn + l * 4;

    short8 kf[2][2], vf[2][2];

    #define STAGE(buf, kt_) do {                                              \
        const size_t k8 = (size_t)(k00 + (kt_) * 32) * 8;                     \
        ld16(dsrcA + k8, &dl[buf][h][0]);                                     \
        ld16(dsrcB + k8, &dl[buf][h + 8][0]);                                 \
    } while (0)

    #define KVLOAD(set, kt_) do {                                             \
        const int k0v = k00 + (kt_) * 32;                                      \
        kf[set][0] = *(const short8*)(kb + (k0v + n) * HDn + h * CHn + g * 8);      \
        kf[set][1] = *(const short8*)(kb + (k0v + 16 + n) * HDn + h * CHn + g * 8); \
        vf[set][0] = *(const short8*)(vtb + (h * CHn + n) * Kn + k0v + g * 8);      \
        vf[set][1] = *(const short8*)(vtb + (h * CHn + 16 + n) * Kn + k0v + g * 8); \
    } while (0)

    // prologue: bias rows (2h, 2h+1), STAGE(0), KVLOAD(0), STAGE(1)
    ld16(bias + (size_t)(q0 + 2 * h) * Kn + k00 + l * 4, bl + (2 * h) * BSTR);
    ld16(bias + (size_t)(q0 + 2 * h + 1) * Kn + k00 + l * 4, bl + (2 * h + 1) * BSTR);
    __builtin_amdgcn_sched_barrier(0);
    STAGE(0, 0);
    __builtin_amdgcn_sched_barrier(0);
    KVLOAD(0, 0);
    __builtin_amdgcn_sched_barrier(0);
    STAGE(1, 1);
    __builtin_amdgcn_sched_barrier(0);

    #pragma unroll
    for (int kt = 0; kt < 8; ++kt) {
        const int cb = kt % 3;
        const int cur = kt & 1;
        // counted drain: retire exactly STAGE(kt) (+bias at kt=0); leave
        // KVLOAD(kt) + STAGE(kt+1) in flight across the barrier.
        if (kt < 7) asm volatile("s_waitcnt vmcnt(6)\n\ts_barrier" ::: "memory");
        else        asm volatile("s_waitcnt vmcnt(4)\n\ts_barrier" ::: "memory");
        if (kt < 7) { KVLOAD(cur ^ 1, kt + 1); __builtin_amdgcn_sched_barrier(0); }
        if (kt < 6) { STAGE((kt + 2) % 3, kt + 2); __builtin_amdgcn_sched_barrier(0); }

        // QK^T (compiler-counted wait retires KVLOAD(kt), leaves stages in flight)
        f32x4 sf[2];
        sf[0] = __builtin_amdgcn_mfma_f32_16x16x32_bf16(qf, kf[cur][0], z, 0, 0, 0);
        sf[1] = __builtin_amdgcn_mfma_f32_16x16x32_bf16(qf, kf[cur][1], z, 0, 0, 0);

        // p = exp(s + dist + bias); row sums; P -> LDS bf16
        #pragma unroll
        for (int kk = 0; kk < 2; ++kk) {
            #pragma unroll
            for (int r = 0; r < 4; ++r) {
                const int q_l = g * 4 + r;
                const float p = __expf(sf[kk][r]
                                       + dl[cb][q_l][(kk * 16 + n) * 8 + h]
                                       + bl[q_l * BSTR + kt * 32 + kk * 16 + n]);
                sf[kk][r] = p;
                lacc[r] += p;
                psh[q_l * 40 + kk * 16 + n] = f2bf(p);
            }
        }

        // PV (vf already retired by QK's wait)
        const short8 pf = *(const short8*)(psh + n * 40 + g * 8);
        o0 = __builtin_amdgcn_mfma_f32_16x16x32_bf16(pf, vf[cur][0], o0, 0, 0, 0);
        o1 = __builtin_amdgcn_mfma_f32_16x16x32_bf16(pf, vf[cur][1], o1, 0, 0, 0);
    }
    #undef STAGE
    #undef KVLOAD

    // write partial O and row-sums
    float* op = opart + (size_t)sp * (Qn * HDn);
    #pragma unroll
    for (int r = 0; r < 4; ++r) {
        const int qg = q0 + g * 4 + r;
        op[qg * HDn + h * CHn + n] = o0[r];
        op[qg * HDn + h * CHn + 16 + n] = o1[r];
        float v = lacc[r];
        v += __shfl_xor(v, 1);
        v += __shfl_xor(v, 2);
        v += __shfl_xor(v, 4);
        v += __shfl_xor(v, 8);
        lacc[r] = v;
    }
    if (n == 0) {
        float* lp = lpart + (size_t)sp * (Qn * Hn);
        #pragma unroll
        for (int r = 0; r < 4; ++r)
            lp[(q0 + g * 4 + r) * Hn + h] = lacc[r];
    }
}

// ---------------------------------------------------------------------------
// K3: merge splits + gating + output projection. One block per q-row.
// ---------------------------------------------------------------------------
__global__ __launch_bounds__(256) void mergeout_kernel(
    const float* __restrict__ opart, const float* __restrict__ lpart,
    const float* __restrict__ gb, const float* __restrict__ Wo,
    const float* __restrict__ bo, float* __restrict__ out)
{
    __shared__ float olds[HDn];
    __shared__ float red[4][128];
    const int q = blockIdx.x;
    const int t = threadIdx.x;
    const int h = t >> 5;
    float s = 0.f;
    #pragma unroll
    for (int sp = 0; sp < NSPLIT; ++sp)
        s += opart[(size_t)sp * (Qn * HDn) + q * HDn + t];
    float lt = 0.f;
    #pragma unroll
    for (int sp = 0; sp < NSPLIT; ++sp)
        lt += lpart[(size_t)sp * (Qn * Hn) + q * Hn + h];
    olds[t] = (s / lt) * gb[q * HDn + t];
    __syncthreads();
    const int p = t & 63;
    const int seg = t >> 6;
    float a0 = 0.f, a1 = 0.f;
    for (int c = seg * 64; c < seg * 64 + 64; ++c) {
        const float ov = olds[c];
        const float2 w = *(const float2*)(Wo + c * Cin + 2 * p);
        a0 = fmaf(ov, w.x, a0);
        a1 = fmaf(ov, w.y, a1);
    }
    red[seg][2 * p] = a0;
    red[seg][2 * p + 1] = a1;
    __syncthreads();
    if (t < 128)
        out[q * Cin + t] = red[0][t] + red[1][t] + red[2][t] + red[3][t] + bo[t];
}

extern "C" void kernel_launch(void* const* d_in, const int* in_sizes, int n_in,
                              void* d_out, int out_size, void* d_ws, size_t ws_size,
                              hipStream_t stream)
{
    const float* qx   = (const float*)d_in[0];
    const float* kvx  = (const float*)d_in[1];
    const float* bias = (const float*)d_in[2];
    const float* dist = (const float*)d_in[3];
    const float* Wq   = (const float*)d_in[4];
    const float* Wk   = (const float*)d_in[5];
    const float* Wv   = (const float*)d_in[6];
    const float* Wg   = (const float*)d_in[7];
    const float* bg   = (const float*)d_in[8];
    const float* Wo   = (const float*)d_in[9];
    const float* bo   = (const float*)d_in[10];
    float* out = (float*)d_out;

    char* w = (char*)d_ws;
    unsigned short* qb  = (unsigned short*)(w);                  // 1 MB
    unsigned short* kb  = (unsigned short*)(w + (1ull << 20));   // 1 MB
    unsigned short* vtb = (unsigned short*)(w + (2ull << 20));   // 1 MB
    float* gb    = (float*)(w + (3ull << 20));                   // 2 MB
    float* opart = (float*)(w + (5ull << 20));                   // 16 MB (8 splits)
    float* lpart = (float*)(w + (21ull << 20));                  // 512 KB

    proj_kernel<<<dim3(Qn / 8, 4), 256, 0, stream>>>(qx, kvx, Wq, Wk, Wv, Wg, bg, qb, kb, vtb, gb);
    attn_kernel<<<dim3(128 * NSPLIT), 512, 0, stream>>>(qb, kb, vtb, bias, dist, opart, lpart);
    mergeout_kernel<<<dim3(Qn), 256, 0, stream>>>(opart, lpart, gb, Wo, bo, out);
}

// Round 7
// 272.797 us; speedup vs baseline: 1.1500x; 1.0300x over previous
//
#include <hip/hip_runtime.h>
#include <hip/hip_bf16.h>

#define Qn 2048
#define Kn 2048
#define Cin 128
#define Hn 8
#define CHn 32
#define HDn 256
#define NSPLIT 4
#define KVB 64              // k per tile
#define NT 8                // tiles per block (512 / 64)
#define DRW 72              // dist plane row stride (halves): bank-rotates q by 4
#define DPL (16 * DRW)      // plane stride (halves)
#define DBUFH (Hn * DPL)    // halves per dist buffer = 9216

typedef __attribute__((ext_vector_type(8))) short short8;
typedef __attribute__((ext_vector_type(4))) float f32x4;

static __device__ __forceinline__ unsigned short f2bf(float f) {
    unsigned int u = __float_as_uint(f);
    u += 0x7fffu + ((u >> 16) & 1u);
    return (unsigned short)(u >> 16);
}

// ---------------------------------------------------------------------------
// K1: projections. q=(qx@Wq)/sqrt(CH)->bf16 [Q][HD]; k=kvx@Wk->bf16 [K][HD];
//     v=kvx@Wv->bf16 TRANSPOSED [HD][K]; g=sigmoid(qx@Wg+bg)->f32 [Q][HD].
// ---------------------------------------------------------------------------
__global__ __launch_bounds__(256) void proj_kernel(
    const float* __restrict__ qx, const float* __restrict__ kvx,
    const float* __restrict__ Wq, const float* __restrict__ Wk,
    const float* __restrict__ Wv, const float* __restrict__ Wg,
    const float* __restrict__ bg,
    unsigned short* __restrict__ qb, unsigned short* __restrict__ kb,
    unsigned short* __restrict__ vtb, float* __restrict__ gb)
{
    const int mat = blockIdx.y;
    const int r0 = blockIdx.x * 8;
    const int j = threadIdx.x;
    const float* A = (mat == 0 || mat == 3) ? qx : kvx;
    const float* W = (mat == 0) ? Wq : (mat == 1) ? Wk : (mat == 2) ? Wv : Wg;
    const float* Ar = A + r0 * Cin;
    float acc[8] = {0.f, 0.f, 0.f, 0.f, 0.f, 0.f, 0.f, 0.f};
    for (int c = 0; c < Cin; ++c) {
        const float w = W[c * HDn + j];
        #pragma unroll
        for (int i = 0; i < 8; ++i)
            acc[i] = fmaf(Ar[i * Cin + c], w, acc[i]);
    }
    if (mat == 0) {
        const float s = 0.17677669529663687f; // 1/sqrt(32)
        #pragma unroll
        for (int i = 0; i < 8; ++i)
            qb[(r0 + i) * HDn + j] = f2bf(acc[i] * s);
    } else if (mat == 1) {
        #pragma unroll
        for (int i = 0; i < 8; ++i)
            kb[(r0 + i) * HDn + j] = f2bf(acc[i]);
    } else if (mat == 2) {
        unsigned short tmp[8];
        #pragma unroll
        for (int i = 0; i < 8; ++i) tmp[i] = f2bf(acc[i]);
        *(short8*)(vtb + (size_t)j * Kn + r0) = *(short8*)tmp;
    } else {
        const float b = bg[j];
        #pragma unroll
        for (int i = 0; i < 8; ++i)
            gb[(r0 + i) * HDn + j] = 1.f / (1.f + __expf(-(acc[i] + b)));
    }
}

// ---------------------------------------------------------------------------
// K2: fused attention. Grid 512 = 128 q-tiles x 4 K-splits, 512 thr = 8 waves
// (wave == head). KVB=64, 8 tiles/block, k-range 512/block.
//
// Stream-locality design (R6 resubmit — R6 bench was an infra failure):
// * NSPLIT=4 + KVB=64: each q-row's dist is read as a 16 KB SEQUENTIAL run
//   (2 KB/tile, contiguous across tiles) — 2x run length, half the
//   stream-switch rate of R5's pattern that pinned at 1.2 TB/s.
// * Reg-staged dist: global->reg f32x4 (1 KB/instr coalesced, same as ld16),
//   bias added in-register, converted to fp16, ds_write into per-head planes
//   dl[buf][head][16 q][72]: exp-phase reads are 2-way banked (free) vs the
//   16-way of [k][h] layout, LDS footprint halves, and exp reads ONE fused
//   value. fp16(dist+bias) is the R0/R1 numeric path (passed @3.05e-5).
// * vmcnt-order discipline (R5 lesson): per iter, KV loads issue FIRST,
//   stage loads (tile kt+2) SECOND. The compiler's automatic waits for the
//   convert (stage kt+1, older than this iter's KV) and for QK (KV kt,
//   older than stage kt+2) then never retire the deep-stage loads.
//   Depth-2 register pipeline, 3 LDS buffers, ONE barrier/iter, no manual
//   vmcnt at all.
// LDS: 3*18432 (dist) + 18432 (ps) = 72 KB -> 2 blocks/CU (16 waves).
// No-max softmax safe: |logit| < 8.
// ---------------------------------------------------------------------------
__global__ __launch_bounds__(512, 4) void attn_kernel(
    const unsigned short* __restrict__ qb, const unsigned short* __restrict__ kb,
    const unsigned short* __restrict__ vtb,
    const float* __restrict__ bias, const float* __restrict__ dist,
    float* __restrict__ opart, float* __restrict__ lpart)
{
    __shared__ _Float16 dl[3 * DBUFH];           // 54 KB  [buf][head][q][72]
    __shared__ unsigned short ps[Hn * 16 * DRW]; // 18 KB  [head][q][72] P round-trip

    const int bx = blockIdx.x;
    const int qt = bx >> 2;
    const int sp = bx & 3;
    const int q0 = qt * 16;
    const int k00 = sp * 512;
    const int t = threadIdx.x;
    const int h = t >> 6;   // wave id == head
    const int l = t & 63;
    const int g = l >> 4;
    const int n = l & 15;
    const int le = l & 1;   // staging: parity selects heads 0-3 vs 4-7
    const int kc = l >> 1;  // staging: k within 32-chunk

    const short8 qf = *(const short8*)(qb + (q0 + n) * HDn + h * CHn + g * 8);

    f32x4 o0 = {0.f, 0.f, 0.f, 0.f};
    f32x4 o1 = {0.f, 0.f, 0.f, 0.f};
    float lacc[4] = {0.f, 0.f, 0.f, 0.f};
    unsigned short* psh = &ps[h * 16 * DRW];
    const f32x4 z = {0.f, 0.f, 0.f, 0.f};

    // stage registers: 2 sets (ping-pong by tile parity) x 4 chunks
    // chunk rc = (row<<1)|c : row -> q-local {h, h+8}, c -> k-half of 64
    f32x4 sreg[2][4];
    float breg[2][4];

    // per instruction: lane l loads 16 B at rowbase + c*1KB + l*16 -> its 4
    // floats are heads {4*le..4*le+3} of k-local kc (global layout [k][h]).
    #define STAGELOAD(set, kt_) do {                                          \
        const size_t kb0 = (size_t)(k00 + (kt_) * KVB);                       \
        _Pragma("unroll") for (int rc = 0; rc < 4; ++rc) {                    \
            const int qloc = h + 8 * (rc >> 1);                               \
            const int c_ = rc & 1;                                            \
            sreg[set][rc] = *(const f32x4*)(dist +                            \
                ((size_t)(q0 + qloc) * Kn + kb0 + c_ * 32) * Hn + l * 4);     \
            breg[set][rc] = bias[(size_t)(q0 + qloc) * Kn + kb0 + c_ * 32 + kc]; \
        }                                                                     \
    } while (0)

    // convert + scatter into per-head planes (banks ~2-way on both sides)
    #define CW(set, buf) do {                                                 \
        _Float16* db_ = dl + (buf) * DBUFH;                                   \
        _Pragma("unroll") for (int rc = 0; rc < 4; ++rc) {                    \
            const int qloc = h + 8 * (rc >> 1);                               \
            const int c_ = rc & 1;                                            \
            _Pragma("unroll") for (int j = 0; j < 4; ++j)                     \
                db_[(4 * le + j) * DPL + qloc * DRW + c_ * 32 + kc] =         \
                    (_Float16)(sreg[set][rc][j] + breg[set][rc]);             \
        }                                                                     \
    } while (0)

    // prologue: load tiles 0,1; convert/publish tile 0
    STAGELOAD(0, 0);
    __builtin_amdgcn_sched_barrier(0);
    STAGELOAD(1, 1);
    __builtin_amdgcn_sched_barrier(0);
    CW(0, 0);
    asm volatile("s_waitcnt lgkmcnt(0)\n\ts_barrier" ::: "memory");

    #pragma unroll
    for (int kt = 0; kt < NT; ++kt) {
        const int k0 = k00 + kt * KVB;

        // KV for THIS tile first (oldest VMEM this iter; L2-hot)
        short8 kf[4], vf[2][2];
        #pragma unroll
        for (int kkg = 0; kkg < 4; ++kkg)
            kf[kkg] = *(const short8*)(kb + (k0 + kkg * 16 + n) * HDn + h * CHn + g * 8);
        #pragma unroll
        for (int c = 0; c < 2; ++c) {
            vf[c][0] = *(const short8*)(vtb + (h * CHn + n) * Kn + k0 + c * 32 + g * 8);
            vf[c][1] = *(const short8*)(vtb + (h * CHn + 16 + n) * Kn + k0 + c * 32 + g * 8);
        }
        __builtin_amdgcn_sched_barrier(0);
        // deep stage for tile kt+2 (younger than KV -> survives all waits)
        if (kt + 2 < NT) { STAGELOAD(kt & 1, kt + 2); __builtin_amdgcn_sched_barrier(0); }
        // convert tile kt+1 (compiler auto-waits exactly its stage loads)
        if (kt + 1 < NT) { CW((kt + 1) & 1, (kt + 1) % 3); }
        if (kt + 1 < NT) { asm volatile("s_waitcnt lgkmcnt(0)\n\ts_barrier" ::: "memory"); }

        // QK^T (auto-wait retires KV(kt); stage(kt+2) stays in flight)
        f32x4 sf[4];
        #pragma unroll
        for (int kkg = 0; kkg < 4; ++kkg)
            sf[kkg] = __builtin_amdgcn_mfma_f32_16x16x32_bf16(qf, kf[kkg], z, 0, 0, 0);

        // p = exp(s + fused(dist+bias)); row sums; P -> LDS bf16
        const _Float16* dc = dl + (kt % 3) * DBUFH + h * DPL;
        #pragma unroll
        for (int kkg = 0; kkg < 4; ++kkg) {
            #pragma unroll
            for (int r = 0; r < 4; ++r) {
                const int q_l = g * 4 + r;
                const float p = __expf(sf[kkg][r] + (float)dc[q_l * DRW + kkg * 16 + n]);
                sf[kkg][r] = p;
                lacc[r] += p;
                psh[q_l * DRW + kkg * 16 + n] = f2bf(p);
            }
        }

        // PV (wave-local ps; lgkm-ordered by compiler)
        #pragma unroll
        for (int c = 0; c < 2; ++c) {
            const short8 pf = *(const short8*)(psh + n * DRW + c * 32 + g * 8);
            o0 = __builtin_amdgcn_mfma_f32_16x16x32_bf16(pf, vf[c][0], o0, 0, 0, 0);
            o1 = __builtin_amdgcn_mfma_f32_16x16x32_bf16(pf, vf[c][1], o1, 0, 0, 0);
        }
    }
    #undef STAGELOAD
    #undef CW

    // write partial O and row-sums
    float* op = opart + (size_t)sp * (Qn * HDn);
    #pragma unroll
    for (int r = 0; r < 4; ++r) {
        const int qg = q0 + g * 4 + r;
        op[qg * HDn + h * CHn + n] = o0[r];
        op[qg * HDn + h * CHn + 16 + n] = o1[r];
        float v = lacc[r];
        v += __shfl_xor(v, 1);
        v += __shfl_xor(v, 2);
        v += __shfl_xor(v, 4);
        v += __shfl_xor(v, 8);
        lacc[r] = v;
    }
    if (n == 0) {
        float* lp = lpart + (size_t)sp * (Qn * Hn);
        #pragma unroll
        for (int r = 0; r < 4; ++r)
            lp[(q0 + g * 4 + r) * Hn + h] = lacc[r];
    }
}

// ---------------------------------------------------------------------------
// K3: merge splits + gating + output projection. One block per q-row.
// ---------------------------------------------------------------------------
__global__ __launch_bounds__(256) void mergeout_kernel(
    const float* __restrict__ opart, const float* __restrict__ lpart,
    const float* __restrict__ gb, const float* __restrict__ Wo,
    const float* __restrict__ bo, float* __restrict__ out)
{
    __shared__ float olds[HDn];
    __shared__ float red[4][128];
    const int q = blockIdx.x;
    const int t = threadIdx.x;
    const int h = t >> 5;
    float s = 0.f;
    #pragma unroll
    for (int sp = 0; sp < NSPLIT; ++sp)
        s += opart[(size_t)sp * (Qn * HDn) + q * HDn + t];
    float lt = 0.f;
    #pragma unroll
    for (int sp = 0; sp < NSPLIT; ++sp)
        lt += lpart[(size_t)sp * (Qn * Hn) + q * Hn + h];
    olds[t] = (s / lt) * gb[q * HDn + t];
    __syncthreads();
    const int p = t & 63;
    const int seg = t >> 6;
    float a0 = 0.f, a1 = 0.f;
    for (int c = seg * 64; c < seg * 64 + 64; ++c) {
        const float ov = olds[c];
        const float2 w = *(const float2*)(Wo + c * Cin + 2 * p);
        a0 = fmaf(ov, w.x, a0);
        a1 = fmaf(ov, w.y, a1);
    }
    red[seg][2 * p] = a0;
    red[seg][2 * p + 1] = a1;
    __syncthreads();
    if (t < 128)
        out[q * Cin + t] = red[0][t] + red[1][t] + red[2][t] + red[3][t] + bo[t];
}

extern "C" void kernel_launch(void* const* d_in, const int* in_sizes, int n_in,
                              void* d_out, int out_size, void* d_ws, size_t ws_size,
                              hipStream_t stream)
{
    const float* qx   = (const float*)d_in[0];
    const float* kvx  = (const float*)d_in[1];
    const float* bias = (const float*)d_in[2];
    const float* dist = (const float*)d_in[3];
    const float* Wq   = (const float*)d_in[4];
    const float* Wk   = (const float*)d_in[5];
    const float* Wv   = (const float*)d_in[6];
    const float* Wg   = (const float*)d_in[7];
    const float* bg   = (const float*)d_in[8];
    const float* Wo   = (const float*)d_in[9];
    const float* bo   = (const float*)d_in[10];
    float* out = (float*)d_out;

    char* w = (char*)d_ws;
    unsigned short* qb  = (unsigned short*)(w);                  // 1 MB
    unsigned short* kb  = (unsigned short*)(w + (1ull << 20));   // 1 MB
    unsigned short* vtb = (unsigned short*)(w + (2ull << 20));   // 1 MB
    float* gb    = (float*)(w + (3ull << 20));                   // 2 MB
    float* opart = (float*)(w + (5ull << 20));                   // 8 MB (4 splits)
    float* lpart = (float*)(w + (21ull << 20));                  // 256 KB

    proj_kernel<<<dim3(Qn / 8, 4), 256, 0, stream>>>(qx, kvx, Wq, Wk, Wv, Wg, bg, qb, kb, vtb, gb);
    attn_kernel<<<dim3(128 * NSPLIT), 512, 0, stream>>>(qb, kb, vtb, bias, dist, opart, lpart);
    mergeout_kernel<<<dim3(Qn), 256, 0, stream>>>(opart, lpart, gb, Wo, bo, out);
}